// Round 11
// baseline (283.409 us; speedup 1.0000x reference)
//
#include <hip/hip_runtime.h>
#include <hip/hip_cooperative_groups.h>
#include <math.h>

namespace cg = cooperative_groups;

// B=2, N=512, DIM=512, HEADS=8, DIM_HEAD=64
// out[be,mu,z] = FFT1024(S_k*v)[mu] / FFT1024(k_)[mu],  mu in [0,512)
// after a 2x8 (b,h)-DFT; inputs zero-padded 512 -> 1024 on the m axis.
// Gk/Gp layout: [be][m][z] (z fastest).
// GEMM path: split-bf16 MFMA (x=xh+xl, W=wh+wl; 3 MFMAs; residual ~2^-17).

#define DIMX 512
#define NPOS 512
#define PADIDX(m) ((m) + ((m) >> 4))
#define SM_BYTES 39168   // max phase LDS: fft 4*1088*8 + 544*8

typedef unsigned short ushort_t;
typedef unsigned int uint_t;
typedef __bf16 bf16x8 __attribute__((ext_vector_type(8)));
typedef float floatx4 __attribute__((ext_vector_type(4)));

static __device__ inline ushort_t f2bf(float f) {
    uint_t u = __float_as_uint(f);
    u = u + 0x7FFFu + ((u >> 16) & 1u);      // round-to-nearest-even
    return (ushort_t)(u >> 16);
}
static __device__ inline float bf2f(ushort_t h) {
    return __uint_as_float(((uint_t)h) << 16);
}

// 8-point DFT twiddles: exp(-2*pi*i*k/8)
__device__ __constant__ float C8[8] = {
    1.f, 0.70710678118654752440f, 0.f, -0.70710678118654752440f,
   -1.f, -0.70710678118654752440f, 0.f, 0.70710678118654752440f };
__device__ __constant__ float S8[8] = {
    0.f, -0.70710678118654752440f, -1.f, -0.70710678118654752440f,
    0.f,  0.70710678118654752440f,  1.f,  0.70710678118654752440f };

// ---------------- phase 0a: x fp32 -> xh + xl (split bf16), [m][k] ----------
static __device__ inline void phase_convx(const float* __restrict__ x,
                                          ushort_t* __restrict__ xh,
                                          ushort_t* __restrict__ xl,
                                          int blk, int t)
{
    const int idx4 = blk * 256 + t;   // 131072 float4 groups total
    const float4 v = ((const float4*)x)[idx4];
    const float vf[4] = {v.x, v.y, v.z, v.w};
    ushort_t h[4], l[4];
    #pragma unroll
    for (int e = 0; e < 4; ++e) {
        h[e] = f2bf(vf[e]);
        l[e] = f2bf(vf[e] - bf2f(h[e]));
    }
    ushort_t* ph = xh + (size_t)idx4 * 4;
    ushort_t* pl = xl + (size_t)idx4 * 4;
    #pragma unroll
    for (int e = 0; e < 4; ++e) { ph[e] = h[e]; pl[e] = l[e]; }
}

// ---------------- phase 0b: Wk|Wv [k][n] -> wth/wtl [n][k] split bf16 -------
// 512 tiles: s = blk>>8 (0=Wk,1=Wv), kt = (blk>>4)&15, nt = blk&15 (32x32)
static __device__ inline void phase_convw(const float* __restrict__ Wk,
                                          const float* __restrict__ Wv,
                                          ushort_t* __restrict__ wth,
                                          ushort_t* __restrict__ wtl,
                                          int blk, int t, char* smraw)
{
    float (*tile)[33] = (float(*)[33])smraw;   // 4224 B
    const int s  = blk >> 8;
    const int kt = (blk >> 4) & 15;
    const int nt = blk & 15;
    const int c  = t & 31, r4 = t >> 5;
    const float* __restrict__ W = s ? Wv : Wk;
    #pragma unroll
    for (int i = 0; i < 4; ++i) {
        const int row = r4 + i * 8;
        tile[row][c] = W[(size_t)(kt * 32 + row) * 512 + nt * 32 + c];
    }
    __syncthreads();
    #pragma unroll
    for (int i = 0; i < 4; ++i) {
        const int nl = r4 + i * 8;
        const float v = tile[c][nl];               // = W[kt*32+c][nt*32+nl]
        const ushort_t h = f2bf(v);
        const ushort_t l = f2bf(v - bf2f(h));
        const size_t o = (size_t)(s * 512 + nt * 32 + nl) * 512 + kt * 32 + c;
        wth[o] = h;
        wtl[o] = l;
    }
}

// ---------------- phase 1: split-bf16 MFMA GEMM, no LDS staging -------------
// ct = blk>>5 (16 col-tiles of 64), rt = blk&31 (32 row-tiles of 32).
// Layouts (m89/m120-verified): A[m=lane&15][k=quad*8+j]; B^T storage [n][k];
// D[row=quad*4+reg][col=lane&15].
static __device__ inline void phase_gemm(const ushort_t* __restrict__ xh,
                                         const ushort_t* __restrict__ xl,
                                         const ushort_t* __restrict__ wth,
                                         const ushort_t* __restrict__ wtl,
                                         float* __restrict__ K,
                                         float* __restrict__ V,
                                         float* __restrict__ partials,
                                         int blk, int t, char* smraw)
{
    float* red = (float*)smraw;       // 16 B
    const int ct = blk >> 5;
    const int rt = blk & 31;
    const int w = t >> 6, lane = t & 63;
    const int qd = lane >> 4, lm = lane & 15;
    const int mrow  = rt * 32 + (w >> 1) * 16 + lm;
    const int ncol0 = ct * 64 + (w & 1) * 32;
    const size_t aoff  = (size_t)mrow * 512 + qd * 8;
    const size_t boff0 = (size_t)(ncol0 + lm) * 512 + qd * 8;
    const size_t boff1 = (size_t)(ncol0 + 16 + lm) * 512 + qd * 8;

    floatx4 acc0 = {0.f, 0.f, 0.f, 0.f};
    floatx4 acc1 = {0.f, 0.f, 0.f, 0.f};

    #pragma unroll
    for (int ks = 0; ks < 16; ++ks) {
        const int k0 = ks * 32;
        const bf16x8 Ah  = *(const bf16x8*)&xh [aoff  + k0];
        const bf16x8 Al  = *(const bf16x8*)&xl [aoff  + k0];
        const bf16x8 B0h = *(const bf16x8*)&wth[boff0 + k0];
        const bf16x8 B0l = *(const bf16x8*)&wtl[boff0 + k0];
        const bf16x8 B1h = *(const bf16x8*)&wth[boff1 + k0];
        const bf16x8 B1l = *(const bf16x8*)&wtl[boff1 + k0];
        acc0 = __builtin_amdgcn_mfma_f32_16x16x32_bf16(Ah, B0h, acc0, 0, 0, 0);
        acc0 = __builtin_amdgcn_mfma_f32_16x16x32_bf16(Ah, B0l, acc0, 0, 0, 0);
        acc0 = __builtin_amdgcn_mfma_f32_16x16x32_bf16(Al, B0h, acc0, 0, 0, 0);
        acc1 = __builtin_amdgcn_mfma_f32_16x16x32_bf16(Ah, B1h, acc1, 0, 0, 0);
        acc1 = __builtin_amdgcn_mfma_f32_16x16x32_bf16(Ah, B1l, acc1, 0, 0, 0);
        acc1 = __builtin_amdgcn_mfma_f32_16x16x32_bf16(Al, B1h, acc1, 0, 0, 0);
    }

    float ss = 0.f;
    const int orow0 = rt * 32 + (w >> 1) * 16 + qd * 4;
    float* __restrict__ O = (ct < 8) ? K : V;
    const int cb = (ct < 8) ? 0 : 512;
    const int c0 = ncol0 + lm - cb;
    #pragma unroll
    for (int r = 0; r < 4; ++r) {
        const size_t row = orow0 + r;
        const float v0 = acc0[r], v1 = acc1[r];
        O[row * 512 + c0]      = v0;
        O[row * 512 + c0 + 16] = v1;
        if (ct < 8) ss += v0 * v0 + v1 * v1;
    }
    #pragma unroll
    for (int off = 32; off > 0; off >>= 1)
        ss += __shfl_down(ss, off, 64);
    if (lane == 0) red[w] = ss;
    __syncthreads();
    if (t == 0) partials[blk] = red[0] + red[1] + red[2] + red[3];
}

// ---------------- phase 2: elu, S_k, P=S_k*V, 2x8 (b,h)-DFT -----------------
static __device__ inline void phase_stage1(const float* __restrict__ K,
                                           const float* __restrict__ V,
                                           const float* __restrict__ partials,
                                           float2* __restrict__ Gk,
                                           float2* __restrict__ Gp,
                                           int m, int t, char* smraw)
{
    float (*kk)[8][64] = (float(*)[8][64])(smraw);          // 4096 B
    float (*pp)[8][64] = (float(*)[8][64])(smraw + 4096);   // 4096 B
    float (*skp)[4]    = (float(*)[4])(smraw + 8192);       // 256 B
    float (*sk)[8]     = (float(*)[8])(smraw + 8448);       // 64 B
    float* sred        = (float*)(smraw + 8512);            // 16 B

    float p = partials[t] + partials[t + 256];
    #pragma unroll
    for (int off = 32; off > 0; off >>= 1)
        p += __shfl_down(p, off, 64);
    if ((t & 63) == 0) sred[t >> 6] = p;
    __syncthreads();
    const float scale = (float)(1.0 / sqrt((double)sred[0] + (double)sred[1] +
                                           (double)sred[2] + (double)sred[3]));

    for (int e = t; e < 1024; e += 256) {
        const int b = e >> 9, rem = e & 511, h = rem >> 6, z = rem & 63;
        const size_t src = (size_t)(b * 512 + m) * DIMX + h * 64 + z;
        const float kv = K[src] * scale;
        kk[b][h][z] = kv > 0.f ? kv : expm1f(kv);
        pp[b][h][z] = V[src];
    }
    __syncthreads();
    if (t < 64) {
        const int bh = t >> 2, q = t & 3;
        float s = 0.f;
        #pragma unroll
        for (int zz = 0; zz < 16; ++zz) s += kk[bh >> 3][bh & 7][q * 16 + zz];
        skp[bh][q] = s;
    }
    __syncthreads();
    if (t < 16) sk[t >> 3][t & 7] = skp[t][0] + skp[t][1] + skp[t][2] + skp[t][3];
    __syncthreads();
    for (int e = t; e < 1024; e += 256) {
        const int b = e >> 9, rem = e & 511, h = rem >> 6, z = rem & 63;
        pp[b][h][z] *= sk[b][h];
    }
    __syncthreads();

    for (int e2 = t; e2 < 512; e2 += 256) {
        const int be = e2 >> 5;
        const int zp = e2 & 31;
        const int beta = be >> 3, eta = be & 7;
        float4 rk, rp;
        #pragma unroll
        for (int zz = 0; zz < 2; ++zz) {
            const int z = zp * 2 + zz;
            float gkr = 0.f, gki = 0.f, gpr = 0.f, gpi = 0.f;
            #pragma unroll
            for (int b = 0; b < 2; ++b) {
                const float sgn = (beta & b) ? -1.f : 1.f;
                #pragma unroll
                for (int h = 0; h < 8; ++h) {
                    const int ph = (eta * h) & 7;
                    const float cr = C8[ph], ci = S8[ph];
                    const float a = kk[b][h][z] * sgn;
                    gkr = fmaf(a, cr, gkr); gki = fmaf(a, ci, gki);
                    const float p2 = pp[b][h][z] * sgn;
                    gpr = fmaf(p2, cr, gpr); gpi = fmaf(p2, ci, gpi);
                }
            }
            if (zz == 0) { rk.x = gkr; rk.y = gki; rp.x = gpr; rp.y = gpi; }
            else         { rk.z = gkr; rk.w = gki; rp.z = gpr; rp.w = gpi; }
        }
        const size_t o = ((size_t)be * NPOS + m) * 64 + zp * 2;
        *(float4*)&Gk[o] = rk;
        *(float4*)&Gp[o] = rp;
    }
}

// ---------------- phase 3: zero-padded 1024-pt radix-2 DIF FFT + divide -----
static __device__ inline void phase_fft(const float2* __restrict__ Gk,
                                        const float2* __restrict__ Gp,
                                        float* __restrict__ out, int out_cplx,
                                        int blk, int t, char* smraw)
{
    float2 (*g)[1088] = (float2(*)[1088])smraw;      // 34816 B
    float2* w = (float2*)(smraw + 34816);            // 4352 B

    const int j  = blk & 7;
    const int l  = (blk >> 3) & 3;
    const int be = blk >> 5;
    const int zg = j * 4 + l;            // z = 2*zg, 2*zg+1

    for (int jj = t; jj < 512; jj += 256) {
        double s, cc;
        sincos(-6.2831853071795864769 * (double)jj / 1024.0, &s, &cc);
        w[PADIDX(jj)] = make_float2((float)cc, (float)s);
    }
    __syncthreads();

    for (int e = t; e < 1024; e += 256) {
        const int a = e >> 9;            // 0 -> Gk, 1 -> Gp
        const int m = e & 511;
        const float4 v4 = *(const float4*)&(a ? Gp : Gk)[((size_t)be * NPOS + m) * 64 + zg * 2];
        const float2 v0 = make_float2(v4.x, v4.y);
        const float2 v1 = make_float2(v4.z, v4.w);
        const float2 tw = w[PADIDX(m)];
        g[a * 2 + 0][PADIDX(m)] = v0;
        g[a * 2 + 1][PADIDX(m)] = v1;
        g[a * 2 + 0][PADIDX(m + 512)] = make_float2(v0.x * tw.x - v0.y * tw.y,
                                                    v0.x * tw.y + v0.y * tw.x);
        g[a * 2 + 1][PADIDX(m + 512)] = make_float2(v1.x * tw.x - v1.y * tw.y,
                                                    v1.x * tw.y + v1.y * tw.x);
    }
    __syncthreads();

    #pragma unroll
    for (int s = 1; s <= 9; ++s) {
        const int S = 512 >> s;
        const int lg = 9 - s;
        #pragma unroll
        for (int q = 0; q < 8; ++q) {
            const int B    = t + 256 * q;
            const int arr  = B >> 9;
            const int beta = B & 511;
            const int jb   = beta & (S - 1);
            const int seg  = beta >> lg;
            const int u    = (seg << (lg + 1)) + jb;
            const int v    = u + S;
            const float2 tw = w[PADIDX(jb << s)];
            const float2 A  = g[arr][PADIDX(u)];
            const float2 Bb = g[arr][PADIDX(v)];
            g[arr][PADIDX(u)] = make_float2(A.x + Bb.x, A.y + Bb.y);
            const float sr = A.x - Bb.x, si = A.y - Bb.y;
            g[arr][PADIDX(v)] = make_float2(sr * tw.x - si * tw.y,
                                            sr * tw.y + si * tw.x);
        }
        __syncthreads();
    }

    for (int e2 = t; e2 < 512; e2 += 256) {
        const int i  = e2;
        const int pi = PADIDX(2 * i);
        const int mu = (int)(__brev((unsigned)i) >> 23);   // bitrev9
        float4 res;
        #pragma unroll
        for (int zi = 0; zi < 2; ++zi) {
            const float2 D  = g[zi][pi];
            const float2 Nm = g[2 + zi][pi];
            const float inv = 1.f / (D.x * D.x + D.y * D.y);
            const float rr = (Nm.x * D.x + Nm.y * D.y) * inv;
            const float ri = (Nm.y * D.x - Nm.x * D.y) * inv;
            if (zi == 0) { res.x = rr; res.y = ri; }
            else         { res.z = rr; res.w = ri; }
        }
        const size_t o = ((size_t)be * NPOS + mu) * 64 + zg * 2;
        if (out_cplx) {
            *(float4*)&((float2*)out)[o] = res;
        } else {
            out[o]     = res.x;
            out[o + 1] = res.z;
        }
    }
}

// ---------------- fused cooperative kernel: 1 dispatch, 3 grid syncs --------
__global__ __launch_bounds__(256, 2)
void fused_kernel(const float* __restrict__ x,
                  const float* __restrict__ Wk, const float* __restrict__ Wv,
                  ushort_t* __restrict__ xh, ushort_t* __restrict__ xl,
                  ushort_t* __restrict__ wth, ushort_t* __restrict__ wtl,
                  float* __restrict__ K, float* __restrict__ V,
                  float* __restrict__ partials,
                  float2* __restrict__ Gk, float2* __restrict__ Gp,
                  float* __restrict__ out, int out_cplx)
{
    cg::grid_group grid = cg::this_grid();
    __shared__ __align__(16) char smraw[SM_BYTES];
    const int blk = blockIdx.x;
    const int t = threadIdx.x;
    phase_convx(x, xh, xl, blk, t);
    phase_convw(Wk, Wv, wth, wtl, blk, t, smraw);
    grid.sync();
    phase_gemm(xh, xl, wth, wtl, K, V, partials, blk, t, smraw);
    grid.sync();
    phase_stage1(K, V, partials, Gk, Gp, blk, t, smraw);
    grid.sync();
    phase_fft(Gk, Gp, out, out_cplx, blk, t, smraw);
}

// ---------------- standalone kernels (fallback if coop launch fails) --------
__global__ __launch_bounds__(256)
void convx_kernel(const float* __restrict__ x,
                  ushort_t* __restrict__ xh, ushort_t* __restrict__ xl)
{ phase_convx(x, xh, xl, blockIdx.x, threadIdx.x); }

__global__ __launch_bounds__(256)
void convw_kernel(const float* __restrict__ Wk, const float* __restrict__ Wv,
                  ushort_t* __restrict__ wth, ushort_t* __restrict__ wtl)
{
    __shared__ __align__(16) char sm[4224];
    phase_convw(Wk, Wv, wth, wtl, blockIdx.x, threadIdx.x, sm);
}

__global__ __launch_bounds__(256)
void gemm_mfma_kernel(const ushort_t* __restrict__ xh, const ushort_t* __restrict__ xl,
                      const ushort_t* __restrict__ wth, const ushort_t* __restrict__ wtl,
                      float* __restrict__ K, float* __restrict__ V,
                      float* __restrict__ partials)
{
    __shared__ __align__(16) char sm[16];
    phase_gemm(xh, xl, wth, wtl, K, V, partials, blockIdx.x, threadIdx.x, sm);
}

__global__ __launch_bounds__(256)
void stage1_kernel(const float* __restrict__ K, const float* __restrict__ V,
                   const float* __restrict__ partials,
                   float2* __restrict__ Gk, float2* __restrict__ Gp)
{
    __shared__ __align__(16) char sm[8528];
    phase_stage1(K, V, partials, Gk, Gp, blockIdx.x, threadIdx.x, sm);
}

__global__ __launch_bounds__(256)
void fft_div_kernel(const float2* __restrict__ Gk, const float2* __restrict__ Gp,
                    float* __restrict__ out, int out_cplx)
{
    __shared__ __align__(16) char sm[SM_BYTES];
    phase_fft(Gk, Gp, out, out_cplx, blockIdx.x, threadIdx.x, sm);
}

// ---------------- small-ws fallback: fp32 GEMM + fp64 mdft ------------------
__global__ __launch_bounds__(256)
void gemm_kv_kernel(const float* __restrict__ x,
                    const float* __restrict__ Wk,
                    const float* __restrict__ Wv,
                    float* __restrict__ K,
                    float* __restrict__ V,
                    float* __restrict__ partials)
{
    const int blk  = blockIdx.x;
    const int sel  = (blk >> 2) & 1;
    const int cg2  = blk & 3;
    const int rt   = blk >> 3;
    const int row0 = rt * 16;
    const int col0 = cg2 * 128;
    const int t    = threadIdx.x;
    const int tc   = t & 31;
    const int tr   = t >> 5;
    const float* __restrict__ W   = sel ? Wv : Wk;
    float* __restrict__       Out = sel ? V  : K;

    __shared__ float xs[16][DIMX];
    __shared__ float red[4];

    #pragma unroll
    for (int j = 0; j < 8; ++j) {
        const int f = t + j * 256;
        const int row = f >> 7, c4 = f & 127;
        *(float4*)&xs[row][c4 * 4] = *(const float4*)&x[(size_t)(row0 + row) * DIMX + c4 * 4];
    }
    __syncthreads();

    const float* Wb = W + col0 + tc * 4;
    float4 wA[8], wB[8];
    #pragma unroll
    for (int j = 0; j < 8; ++j) wA[j] = *(const float4*)&Wb[(size_t)(j) * DIMX];
    #pragma unroll
    for (int j = 0; j < 8; ++j) wB[j] = *(const float4*)&Wb[(size_t)(8 + j) * DIMX];

    float acc[2][4] = {{0,0,0,0},{0,0,0,0}};
    const int r0 = tr * 2;

    #define COMPUTE_CHUNK(WREG, CH)                                            \
        {   float4 xv0a = *(const float4*)&xs[r0][(CH) * 8];                   \
            float4 xv0b = *(const float4*)&xs[r0][(CH) * 8 + 4];               \
            float4 xv1a = *(const float4*)&xs[r0 + 1][(CH) * 8];               \
            float4 xv1b = *(const float4*)&xs[r0 + 1][(CH) * 8 + 4];           \
            _Pragma("unroll")                                                  \
            for (int kk = 0; kk < 4; ++kk) {                                   \
                const float x0 = (&xv0a.x)[kk], x1 = (&xv1a.x)[kk];            \
                _Pragma("unroll")                                              \
                for (int cc = 0; cc < 4; ++cc) {                               \
                    acc[0][cc] = fmaf(x0, (&WREG[kk].x)[cc], acc[0][cc]);      \
                    acc[1][cc] = fmaf(x1, (&WREG[kk].x)[cc], acc[1][cc]);      \
                } }                                                            \
            _Pragma("unroll")                                                  \
            for (int kk = 0; kk < 4; ++kk) {                                   \
                const float x0 = (&xv0b.x)[kk], x1 = (&xv1b.x)[kk];            \
                _Pragma("unroll")                                              \
                for (int cc = 0; cc < 4; ++cc) {                               \
                    acc[0][cc] = fmaf(x0, (&WREG[kk + 4].x)[cc], acc[0][cc]);  \
                    acc[1][cc] = fmaf(x1, (&WREG[kk + 4].x)[cc], acc[1][cc]);  \
                } } }

    for (int ch = 0; ch < 64; ch += 2) {
        COMPUTE_CHUNK(wA, ch)
        if (ch < 62) {
            #pragma unroll
            for (int j = 0; j < 8; ++j)
                wA[j] = *(const float4*)&Wb[(size_t)((ch + 2) * 8 + j) * DIMX];
        }
        COMPUTE_CHUNK(wB, ch + 1)
        if (ch < 62) {
            #pragma unroll
            for (int j = 0; j < 8; ++j)
                wB[j] = *(const float4*)&Wb[(size_t)((ch + 3) * 8 + j) * DIMX];
        }
    }
    #undef COMPUTE_CHUNK

    float ss = 0.f;
    #pragma unroll
    for (int i = 0; i < 2; ++i) {
        const int row = row0 + r0 + i;
        const float4 o = make_float4(acc[i][0], acc[i][1], acc[i][2], acc[i][3]);
        *(float4*)&Out[(size_t)row * DIMX + col0 + tc * 4] = o;
        ss += o.x * o.x + o.y * o.y + o.z * o.z + o.w * o.w;
    }
    if (sel == 0) {
        #pragma unroll
        for (int off = 32; off > 0; off >>= 1)
            ss += __shfl_down(ss, off, 64);
        if ((t & 63) == 0) red[t >> 6] = ss;
        __syncthreads();
        if (t == 0) partials[blk] = red[0] + red[1] + red[2] + red[3];
    } else {
        if (t == 0) partials[blk] = 0.f;
    }
}

__global__ __launch_bounds__(256)
void mdft_fallback_kernel(const float2* __restrict__ Gk,
                          const float2* __restrict__ Gp,
                          float* __restrict__ out,
                          int out_cplx)
{
    const int blk = blockIdx.x;
    const int be = blk >> 6, z = blk & 63;
    const int t = threadIdx.x;
    __shared__ float2 gk[512];
    __shared__ float2 gp[512];
    __shared__ float2 w[1024];

    for (int m = t; m < 512; m += 256) {
        const size_t idx = ((size_t)be * NPOS + m) * 64 + z;
        gk[m] = Gk[idx];
        gp[m] = Gp[idx];
    }
    for (int jj = t; jj < 1024; jj += 256) {
        double s, c;
        sincos(-6.2831853071795864769 * (double)jj / 1024.0, &s, &c);
        w[jj] = make_float2((float)c, (float)s);
    }
    __syncthreads();

    #pragma unroll
    for (int half = 0; half < 2; ++half) {
        const int mu = t + half * 256;
        double dr = 0.0, di = 0.0, nr = 0.0, ni = 0.0;
        int idx = 0;
        for (int m = 0; m < 512; ++m) {
            const float2 tw = w[idx];
            idx = (idx + mu) & 1023;
            const float2 a = gk[m];
            dr += (double)(a.x * tw.x - a.y * tw.y);
            di += (double)(a.x * tw.y + a.y * tw.x);
            const float2 p = gp[m];
            nr += (double)(p.x * tw.x - p.y * tw.y);
            ni += (double)(p.x * tw.y + p.y * tw.x);
        }
        const double dmag = dr * dr + di * di;
        const double orr = (nr * dr + ni * di) / dmag;
        const double oii = (ni * dr - nr * di) / dmag;
        const size_t o = ((size_t)be * NPOS + mu) * 64 + z;
        if (out_cplx) {
            out[2 * o]     = (float)orr;
            out[2 * o + 1] = (float)oii;
        } else {
            out[o] = (float)orr;
        }
    }
}

extern "C" void kernel_launch(void* const* d_in, const int* in_sizes, int n_in,
                              void* d_out, int out_size, void* d_ws, size_t ws_size,
                              hipStream_t stream)
{
    // inputs: x, Wq, Wk, Wv, Er — only x, Wk, Wv needed
    const float* x  = (const float*)d_in[0];
    const float* Wk = (const float*)d_in[2];
    const float* Wv = (const float*)d_in[3];
    float* out = (float*)d_out;

    char* ws = (char*)d_ws;
    float*  K    = (float*)(ws);                           // 2 MB
    float*  V    = (float*)(ws + (size_t)2097152);         // 2 MB
    float2* Gk   = (float2*)(ws + (size_t)4194304);        // 4 MB
    float*  part = (float*)(ws + (size_t)8388608);         // 2 KB (512 floats)
    const int out_cplx = (out_size >= 2 * 2 * 8 * 512 * 64) ? 1 : 0;

    const bool ws_big = (ws_size >= (size_t)20971520);     // needs 20 MB
    float2* Gp = ws_big ? (float2*)(ws + (size_t)8390656)  // 4 MB
                        : (float2*)d_out;                  // alias-safe fallback

    if (ws_big) {
        ushort_t* xh  = (ushort_t*)(ws + (size_t)16777216);  // 1 MB each
        ushort_t* xl  = (ushort_t*)(ws + (size_t)17825792);
        ushort_t* wth = (ushort_t*)(ws + (size_t)18874368);
        ushort_t* wtl = (ushort_t*)(ws + (size_t)19922944);

        const float* xa = x; const float* wka = Wk; const float* wva = Wv;
        ushort_t* xha = xh; ushort_t* xla = xl;
        ushort_t* wtha = wth; ushort_t* wtla = wtl;
        float* Ka = K; float* Va = V; float* pa = part;
        float2* Gka = Gk; float2* Gpa = Gp; float* oa = out;
        int oc = out_cplx;
        void* args[] = { &xa, &wka, &wva, &xha, &xla, &wtha, &wtla,
                         &Ka, &Va, &pa, &Gka, &Gpa, &oa, &oc };
        hipError_t err = hipLaunchCooperativeKernel(
            (const void*)fused_kernel, dim3(512), dim3(256), args, 0, stream);
        if (err != hipSuccess) {
            (void)hipGetLastError();   // clear sticky error, use 5-dispatch path
            hipLaunchKernelGGL(convx_kernel, dim3(512), dim3(256), 0, stream,
                               x, xh, xl);
            hipLaunchKernelGGL(convw_kernel, dim3(512), dim3(256), 0, stream,
                               Wk, Wv, wth, wtl);
            hipLaunchKernelGGL(gemm_mfma_kernel, dim3(512), dim3(256), 0, stream,
                               xh, xl, wth, wtl, K, V, part);
            hipLaunchKernelGGL(stage1_kernel, dim3(512), dim3(256), 0, stream,
                               K, V, part, Gk, Gp);
            hipLaunchKernelGGL(fft_div_kernel, dim3(512), dim3(256), 0, stream,
                               Gk, Gp, out, out_cplx);
        }
    } else {
        hipLaunchKernelGGL(gemm_kv_kernel, dim3(512), dim3(256), 0, stream,
                           x, Wk, Wv, K, V, part);
        hipLaunchKernelGGL(stage1_kernel, dim3(512), dim3(256), 0, stream,
                           K, V, part, Gk, Gp);
        hipLaunchKernelGGL(mdft_fallback_kernel, dim3(1024), dim3(256), 0, stream,
                           Gk, Gp, out, out_cplx);
    }
}

// Round 12
// 109.837 us; speedup vs baseline: 2.5803x; 2.5803x over previous
//
#include <hip/hip_runtime.h>
#include <math.h>

// B=2, N=512, DIM=512, HEADS=8, DIM_HEAD=64
// out[be,mu,z] = FFT1024(S_k*v)[mu] / FFT1024(k_)[mu],  mu in [0,512)
// after a 2x8 (b,h)-DFT; inputs zero-padded 512 -> 1024 on the m axis.
// Gk/Gp layout: [be][m][z] (z fastest).
// GEMM path: split-bf16 MFMA (x=xh+xl, W=wh+wl; 3 MFMAs; residual ~2^-17).
// R11 post-mortem: cooperative fusion regressed (grid.sync ~60us each) —
// reverted to the R10 5-dispatch structure, minus one dispatch (conv merged).

#define DIMX 512
#define NPOS 512
#define PADIDX(m) ((m) + ((m) >> 4))

typedef unsigned short ushort_t;
typedef unsigned int uint_t;
typedef __bf16 bf16x8 __attribute__((ext_vector_type(8)));
typedef float floatx4 __attribute__((ext_vector_type(4)));

static __device__ inline ushort_t f2bf(float f) {
    uint_t u = __float_as_uint(f);
    u = u + 0x7FFFu + ((u >> 16) & 1u);      // round-to-nearest-even
    return (ushort_t)(u >> 16);
}
static __device__ inline float bf2f(ushort_t h) {
    return __uint_as_float(((uint_t)h) << 16);
}

// ---------------- conv (merged): blk<512 -> x split; blk>=512 -> W split+T --
__global__ __launch_bounds__(256)
void conv_kernel(const float* __restrict__ x,
                 const float* __restrict__ Wk, const float* __restrict__ Wv,
                 ushort_t* __restrict__ xh, ushort_t* __restrict__ xl,
                 ushort_t* __restrict__ wth, ushort_t* __restrict__ wtl)
{
    const int blk = blockIdx.x;
    const int t = threadIdx.x;
    if (blk < 512) {
        // x fp32 -> xh + xl, [m][k], one float4 per thread
        const int idx4 = blk * 256 + t;   // 131072 float4 groups
        const float4 v = ((const float4*)x)[idx4];
        const float vf[4] = {v.x, v.y, v.z, v.w};
        ushort_t h[4], l[4];
        #pragma unroll
        for (int e = 0; e < 4; ++e) {
            h[e] = f2bf(vf[e]);
            l[e] = f2bf(vf[e] - bf2f(h[e]));
        }
        ushort_t* ph = xh + (size_t)idx4 * 4;
        ushort_t* pl = xl + (size_t)idx4 * 4;
        #pragma unroll
        for (int e = 0; e < 4; ++e) { ph[e] = h[e]; pl[e] = l[e]; }
    } else {
        // Wk|Wv [k][n] -> wth/wtl [n][k] split bf16, 32x32 LDS transpose
        __shared__ float tile[32][33];
        const int b2 = blk - 512;
        const int s  = b2 >> 8;            // 0=Wk, 1=Wv
        const int kt = (b2 >> 4) & 15;
        const int nt = b2 & 15;
        const int c  = t & 31, r4 = t >> 5;
        const float* __restrict__ W = s ? Wv : Wk;
        #pragma unroll
        for (int i = 0; i < 4; ++i) {
            const int row = r4 + i * 8;
            tile[row][c] = W[(size_t)(kt * 32 + row) * 512 + nt * 32 + c];
        }
        __syncthreads();
        #pragma unroll
        for (int i = 0; i < 4; ++i) {
            const int nl = r4 + i * 8;
            const float v = tile[c][nl];           // = W[kt*32+c][nt*32+nl]
            const ushort_t h = f2bf(v);
            const ushort_t l = f2bf(v - bf2f(h));
            const size_t o = (size_t)(s * 512 + nt * 32 + nl) * 512 + kt * 32 + c;
            wth[o] = h;
            wtl[o] = l;
        }
    }
}

// ---------------- GEMM: split-bf16 MFMA, no LDS staging, no barriers --------
// grid 512: ct = blk>>5 (16 col-tiles of 64), rt = blk&31 (32 row-tiles of 32).
// Layouts (m89/m120-verified): A[m=lane&15][k=quad*8+j]; B^T storage [n][k];
// D[row=quad*4+reg][col=lane&15].
__global__ __launch_bounds__(256)
void gemm_mfma_kernel(const ushort_t* __restrict__ xh, const ushort_t* __restrict__ xl,
                      const ushort_t* __restrict__ wth, const ushort_t* __restrict__ wtl,
                      float* __restrict__ K, float* __restrict__ V,
                      float* __restrict__ partials)
{
    const int blk = blockIdx.x;       // 0..511
    const int ct = blk >> 5;          // 0..15
    const int rt = blk & 31;          // 0..31
    const int t = threadIdx.x;
    const int w = t >> 6, lane = t & 63;
    const int qd = lane >> 4, lm = lane & 15;
    const int mrow  = rt * 32 + (w >> 1) * 16 + lm;
    const int ncol0 = ct * 64 + (w & 1) * 32;
    const size_t aoff  = (size_t)mrow * 512 + qd * 8;
    const size_t boff0 = (size_t)(ncol0 + lm) * 512 + qd * 8;
    const size_t boff1 = (size_t)(ncol0 + 16 + lm) * 512 + qd * 8;

    floatx4 acc0 = {0.f, 0.f, 0.f, 0.f};
    floatx4 acc1 = {0.f, 0.f, 0.f, 0.f};

    #pragma unroll
    for (int ks = 0; ks < 16; ++ks) {
        const int k0 = ks * 32;
        const bf16x8 Ah  = *(const bf16x8*)&xh [aoff  + k0];
        const bf16x8 Al  = *(const bf16x8*)&xl [aoff  + k0];
        const bf16x8 B0h = *(const bf16x8*)&wth[boff0 + k0];
        const bf16x8 B0l = *(const bf16x8*)&wtl[boff0 + k0];
        const bf16x8 B1h = *(const bf16x8*)&wth[boff1 + k0];
        const bf16x8 B1l = *(const bf16x8*)&wtl[boff1 + k0];
        acc0 = __builtin_amdgcn_mfma_f32_16x16x32_bf16(Ah, B0h, acc0, 0, 0, 0);
        acc0 = __builtin_amdgcn_mfma_f32_16x16x32_bf16(Ah, B0l, acc0, 0, 0, 0);
        acc0 = __builtin_amdgcn_mfma_f32_16x16x32_bf16(Al, B0h, acc0, 0, 0, 0);
        acc1 = __builtin_amdgcn_mfma_f32_16x16x32_bf16(Ah, B1h, acc1, 0, 0, 0);
        acc1 = __builtin_amdgcn_mfma_f32_16x16x32_bf16(Ah, B1l, acc1, 0, 0, 0);
        acc1 = __builtin_amdgcn_mfma_f32_16x16x32_bf16(Al, B1h, acc1, 0, 0, 0);
    }

    // epilogue: D[row=quad*4+r][col=lane&15]
    __shared__ float red[4];
    float ss = 0.f;
    const int orow0 = rt * 32 + (w >> 1) * 16 + qd * 4;
    float* __restrict__ O = (ct < 8) ? K : V;
    const int cb = (ct < 8) ? 0 : 512;
    const int c0 = ncol0 + lm - cb;
    #pragma unroll
    for (int r = 0; r < 4; ++r) {
        const size_t row = orow0 + r;
        const float v0 = acc0[r], v1 = acc1[r];
        O[row * 512 + c0]      = v0;
        O[row * 512 + c0 + 16] = v1;
        if (ct < 8) ss += v0 * v0 + v1 * v1;
    }
    #pragma unroll
    for (int off = 32; off > 0; off >>= 1)
        ss += __shfl_down(ss, off, 64);
    if (lane == 0) red[w] = ss;
    __syncthreads();
    if (t == 0) partials[blk] = red[0] + red[1] + red[2] + red[3];
}

// 8-point DFT twiddles: exp(-2*pi*i*k/8)
__device__ __constant__ float C8[8] = {
    1.f, 0.70710678118654752440f, 0.f, -0.70710678118654752440f,
   -1.f, -0.70710678118654752440f, 0.f, 0.70710678118654752440f };
__device__ __constant__ float S8[8] = {
    0.f, -0.70710678118654752440f, -1.f, -0.70710678118654752440f,
    0.f,  0.70710678118654752440f,  1.f,  0.70710678118654752440f };

// elu(K/norm), S_k, P = S_k*V, 2x8 (b,h)-DFT. Writes [be][m][z], float4.
__global__ __launch_bounds__(256)
void stage1_kernel(const float* __restrict__ K,
                   const float* __restrict__ V,
                   const float* __restrict__ partials,
                   float2* __restrict__ Gk,
                   float2* __restrict__ Gp)
{
    const int m = blockIdx.x;     // 0..511
    const int t = threadIdx.x;
    __shared__ float kk[2][8][64];
    __shared__ float pp[2][8][64];
    __shared__ float skp[16][4];
    __shared__ float sk[2][8];
    __shared__ float sred[4];

    // reduce the 512 gemm partials -> global Frobenius scale
    float p = partials[t] + partials[t + 256];
    #pragma unroll
    for (int off = 32; off > 0; off >>= 1)
        p += __shfl_down(p, off, 64);
    if ((t & 63) == 0) sred[t >> 6] = p;
    __syncthreads();
    const float scale = (float)(1.0 / sqrt((double)sred[0] + (double)sred[1] +
                                           (double)sred[2] + (double)sred[3]));

    // float4 loads: thread t covers elements 4t..4t+3 (4 consecutive z)
    {
        const int e0 = t * 4;
        const int b = e0 >> 9, rem = e0 & 511, h = rem >> 6, z = rem & 63;
        const size_t src = (size_t)(b * 512 + m) * DIMX + h * 64 + z;
        const float4 kv4 = *(const float4*)&K[src];
        const float4 vv4 = *(const float4*)&V[src];
        const float kf[4] = {kv4.x, kv4.y, kv4.z, kv4.w};
        const float vf[4] = {vv4.x, vv4.y, vv4.z, vv4.w};
        #pragma unroll
        for (int e = 0; e < 4; ++e) {
            const float kv = kf[e] * scale;
            kk[b][h][z + e] = kv > 0.f ? kv : expm1f(kv);
            pp[b][h][z + e] = vf[e];
        }
    }
    __syncthreads();
    if (t < 64) {               // sk[b][h] = sum_z elu(k): 4 threads per (b,h)
        const int bh = t >> 2, q = t & 3;
        float s = 0.f;
        #pragma unroll
        for (int zz = 0; zz < 16; ++zz) s += kk[bh >> 3][bh & 7][q * 16 + zz];
        skp[bh][q] = s;
    }
    __syncthreads();
    if (t < 16) sk[t >> 3][t & 7] = skp[t][0] + skp[t][1] + skp[t][2] + skp[t][3];
    __syncthreads();
    for (int e = t; e < 1024; e += 256) {
        const int b = e >> 9, rem = e & 511, h = rem >> 6, z = rem & 63;
        pp[b][h][z] *= sk[b][h];
    }
    __syncthreads();

    // 2x8 (b,h)-DFT; each thread computes a z-PAIR -> float4 stores.
    for (int e2 = t; e2 < 512; e2 += 256) {
        const int be = e2 >> 5;          // 0..15
        const int zp = e2 & 31;          // z pair index
        const int beta = be >> 3, eta = be & 7;
        float4 rk, rp;
        #pragma unroll
        for (int zz = 0; zz < 2; ++zz) {
            const int z = zp * 2 + zz;
            float gkr = 0.f, gki = 0.f, gpr = 0.f, gpi = 0.f;
            #pragma unroll
            for (int b = 0; b < 2; ++b) {
                const float sgn = (beta & b) ? -1.f : 1.f;
                #pragma unroll
                for (int h = 0; h < 8; ++h) {
                    const int ph = (eta * h) & 7;
                    const float cr = C8[ph], ci = S8[ph];
                    const float a = kk[b][h][z] * sgn;
                    gkr = fmaf(a, cr, gkr); gki = fmaf(a, ci, gki);
                    const float p2 = pp[b][h][z] * sgn;
                    gpr = fmaf(p2, cr, gpr); gpi = fmaf(p2, ci, gpi);
                }
            }
            if (zz == 0) { rk.x = gkr; rk.y = gki; rp.x = gpr; rp.y = gpi; }
            else         { rk.z = gkr; rk.w = gki; rp.z = gpr; rp.w = gpi; }
        }
        const size_t o = ((size_t)be * NPOS + m) * 64 + zp * 2;
        *(float4*)&Gk[o] = rk;
        *(float4*)&Gp[o] = rp;
    }
}

// ---------------- Zero-padded 1024-pt radix-2 DIF FFT + divide --------------
// Swizzle: blk = be*32 + l*8 + j, zg = j*4 + l  ->  the 4 blocks sharing each
// 64B out-line / Gk-line (zg group of 4, fixed be) have equal blk%8 (same XCD).
__global__ __launch_bounds__(256)
void fft_div_kernel(const float2* __restrict__ Gk,   // [be][m][z]
                    const float2* __restrict__ Gp,
                    float* __restrict__ out, int out_cplx)
{
    const int blk = blockIdx.x;
    const int j  = blk & 7;
    const int l  = (blk >> 3) & 3;
    const int be = blk >> 5;
    const int zg = j * 4 + l;            // z = 2*zg, 2*zg+1
    const int t  = threadIdx.x;

    __shared__ float2 g[4][1088];   // arr = a*2+zi, padded 1024 -> 1088
    __shared__ float2 w[544];       // padded 512 twiddles

    for (int jj = t; jj < 512; jj += 256) {
        double s, cc;
        sincos(-6.2831853071795864769 * (double)jj / 1024.0, &s, &cc);
        w[PADIDX(jj)] = make_float2((float)cc, (float)s);
    }
    __syncthreads();

    // load z-pair as float4 + fused stage 0 (upper half of input is zero)
    for (int e = t; e < 1024; e += 256) {
        const int a = e >> 9;            // 0 -> Gk, 1 -> Gp
        const int m = e & 511;
        const float4 v4 = *(const float4*)&(a ? Gp : Gk)[((size_t)be * NPOS + m) * 64 + zg * 2];
        const float2 v0 = make_float2(v4.x, v4.y);
        const float2 v1 = make_float2(v4.z, v4.w);
        const float2 tw = w[PADIDX(m)];
        g[a * 2 + 0][PADIDX(m)] = v0;
        g[a * 2 + 1][PADIDX(m)] = v1;
        g[a * 2 + 0][PADIDX(m + 512)] = make_float2(v0.x * tw.x - v0.y * tw.y,
                                                    v0.x * tw.y + v0.y * tw.x);
        g[a * 2 + 1][PADIDX(m + 512)] = make_float2(v1.x * tw.x - v1.y * tw.y,
                                                    v1.x * tw.y + v1.y * tw.x);
    }
    __syncthreads();

    #pragma unroll
    for (int s = 1; s <= 9; ++s) {
        const int S = 512 >> s;
        const int lg = 9 - s;
        #pragma unroll
        for (int q = 0; q < 8; ++q) {
            const int B    = t + 256 * q;
            const int arr  = B >> 9;
            const int beta = B & 511;
            const int jb   = beta & (S - 1);
            const int seg  = beta >> lg;
            const int u    = (seg << (lg + 1)) + jb;
            const int v    = u + S;
            const float2 tw = w[PADIDX(jb << s)];
            const float2 A  = g[arr][PADIDX(u)];
            const float2 Bb = g[arr][PADIDX(v)];
            g[arr][PADIDX(u)] = make_float2(A.x + Bb.x, A.y + Bb.y);
            const float sr = A.x - Bb.x, si = A.y - Bb.y;
            g[arr][PADIDX(v)] = make_float2(sr * tw.x - si * tw.y,
                                            sr * tw.y + si * tw.x);
        }
        __syncthreads();
    }

    // even positions 2i hold mu = bitrev9(i). Divide both z and store float4.
    for (int e2 = t; e2 < 512; e2 += 256) {
        const int i  = e2;
        const int pi = PADIDX(2 * i);
        const int mu = (int)(__brev((unsigned)i) >> 23);   // bitrev9
        float4 res;
        #pragma unroll
        for (int zi = 0; zi < 2; ++zi) {
            const float2 D  = g[zi][pi];
            const float2 Nm = g[2 + zi][pi];
            const float inv = 1.f / (D.x * D.x + D.y * D.y);
            const float rr = (Nm.x * D.x + Nm.y * D.y) * inv;
            const float ri = (Nm.y * D.x - Nm.x * D.y) * inv;
            if (zi == 0) { res.x = rr; res.y = ri; }
            else         { res.z = rr; res.w = ri; }
        }
        const size_t o = ((size_t)be * NPOS + mu) * 64 + zg * 2;
        if (out_cplx) {
            *(float4*)&((float2*)out)[o] = res;
        } else {
            out[o]     = res.x;
            out[o + 1] = res.z;
        }
    }
}

// ---------------- small-ws fallback: fp32 GEMM + fp64 mdft ------------------
__global__ __launch_bounds__(256)
void gemm_kv_kernel(const float* __restrict__ x,
                    const float* __restrict__ Wk,
                    const float* __restrict__ Wv,
                    float* __restrict__ K,
                    float* __restrict__ V,
                    float* __restrict__ partials)
{
    const int blk  = blockIdx.x;
    const int sel  = (blk >> 2) & 1;
    const int cg2  = blk & 3;
    const int rt   = blk >> 3;
    const int row0 = rt * 16;
    const int col0 = cg2 * 128;
    const int t    = threadIdx.x;
    const int tc   = t & 31;
    const int tr   = t >> 5;
    const float* __restrict__ W   = sel ? Wv : Wk;
    float* __restrict__       Out = sel ? V  : K;

    __shared__ float xs[16][DIMX];
    __shared__ float red[4];

    #pragma unroll
    for (int j = 0; j < 8; ++j) {
        const int f = t + j * 256;
        const int row = f >> 7, c4 = f & 127;
        *(float4*)&xs[row][c4 * 4] = *(const float4*)&x[(size_t)(row0 + row) * DIMX + c4 * 4];
    }
    __syncthreads();

    const float* Wb = W + col0 + tc * 4;
    float4 wA[8], wB[8];
    #pragma unroll
    for (int j = 0; j < 8; ++j) wA[j] = *(const float4*)&Wb[(size_t)(j) * DIMX];
    #pragma unroll
    for (int j = 0; j < 8; ++j) wB[j] = *(const float4*)&Wb[(size_t)(8 + j) * DIMX];

    float acc[2][4] = {{0,0,0,0},{0,0,0,0}};
    const int r0 = tr * 2;

    #define COMPUTE_CHUNK(WREG, CH)                                            \
        {   float4 xv0a = *(const float4*)&xs[r0][(CH) * 8];                   \
            float4 xv0b = *(const float4*)&xs[r0][(CH) * 8 + 4];               \
            float4 xv1a = *(const float4*)&xs[r0 + 1][(CH) * 8];               \
            float4 xv1b = *(const float4*)&xs[r0 + 1][(CH) * 8 + 4];           \
            _Pragma("unroll")                                                  \
            for (int kk = 0; kk < 4; ++kk) {                                   \
                const float x0 = (&xv0a.x)[kk], x1 = (&xv1a.x)[kk];            \
                _Pragma("unroll")                                              \
                for (int cc = 0; cc < 4; ++cc) {                               \
                    acc[0][cc] = fmaf(x0, (&WREG[kk].x)[cc], acc[0][cc]);      \
                    acc[1][cc] = fmaf(x1, (&WREG[kk].x)[cc], acc[1][cc]);      \
                } }                                                            \
            _Pragma("unroll")                                                  \
            for (int kk = 0; kk < 4; ++kk) {                                   \
                const float x0 = (&xv0b.x)[kk], x1 = (&xv1b.x)[kk];            \
                _Pragma("unroll")                                              \
                for (int cc = 0; cc < 4; ++cc) {                               \
                    acc[0][cc] = fmaf(x0, (&WREG[kk + 4].x)[cc], acc[0][cc]);  \
                    acc[1][cc] = fmaf(x1, (&WREG[kk + 4].x)[cc], acc[1][cc]);  \
                } } }

    for (int ch = 0; ch < 64; ch += 2) {
        COMPUTE_CHUNK(wA, ch)
        if (ch < 62) {
            #pragma unroll
            for (int j = 0; j < 8; ++j)
                wA[j] = *(const float4*)&Wb[(size_t)((ch + 2) * 8 + j) * DIMX];
        }
        COMPUTE_CHUNK(wB, ch + 1)
        if (ch < 62) {
            #pragma unroll
            for (int j = 0; j < 8; ++j)
                wB[j] = *(const float4*)&Wb[(size_t)((ch + 3) * 8 + j) * DIMX];
        }
    }
    #undef COMPUTE_CHUNK

    float ss = 0.f;
    #pragma unroll
    for (int i = 0; i < 2; ++i) {
        const int row = row0 + r0 + i;
        const float4 o = make_float4(acc[i][0], acc[i][1], acc[i][2], acc[i][3]);
        *(float4*)&Out[(size_t)row * DIMX + col0 + tc * 4] = o;
        ss += o.x * o.x + o.y * o.y + o.z * o.z + o.w * o.w;
    }
    if (sel == 0) {
        #pragma unroll
        for (int off = 32; off > 0; off >>= 1)
            ss += __shfl_down(ss, off, 64);
        if ((t & 63) == 0) red[t >> 6] = ss;
        __syncthreads();
        if (t == 0) partials[blk] = red[0] + red[1] + red[2] + red[3];
    } else {
        if (t == 0) partials[blk] = 0.f;
    }
}

__global__ __launch_bounds__(256)
void mdft_fallback_kernel(const float2* __restrict__ Gk,
                          const float2* __restrict__ Gp,
                          float* __restrict__ out,
                          int out_cplx)
{
    const int blk = blockIdx.x;
    const int be = blk >> 6, z = blk & 63;
    const int t = threadIdx.x;
    __shared__ float2 gk[512];
    __shared__ float2 gp[512];
    __shared__ float2 w[1024];

    for (int m = t; m < 512; m += 256) {
        const size_t idx = ((size_t)be * NPOS + m) * 64 + z;
        gk[m] = Gk[idx];
        gp[m] = Gp[idx];
    }
    for (int jj = t; jj < 1024; jj += 256) {
        double s, c;
        sincos(-6.2831853071795864769 * (double)jj / 1024.0, &s, &c);
        w[jj] = make_float2((float)c, (float)s);
    }
    __syncthreads();

    #pragma unroll
    for (int half = 0; half < 2; ++half) {
        const int mu = t + half * 256;
        double dr = 0.0, di = 0.0, nr = 0.0, ni = 0.0;
        int idx = 0;
        for (int m = 0; m < 512; ++m) {
            const float2 tw = w[idx];
            idx = (idx + mu) & 1023;
            const float2 a = gk[m];
            dr += (double)(a.x * tw.x - a.y * tw.y);
            di += (double)(a.x * tw.y + a.y * tw.x);
            const float2 p = gp[m];
            nr += (double)(p.x * tw.x - p.y * tw.y);
            ni += (double)(p.x * tw.y + p.y * tw.x);
        }
        const double dmag = dr * dr + di * di;
        const double orr = (nr * dr + ni * di) / dmag;
        const double oii = (ni * dr - nr * di) / dmag;
        const size_t o = ((size_t)be * NPOS + mu) * 64 + z;
        if (out_cplx) {
            out[2 * o]     = (float)orr;
            out[2 * o + 1] = (float)oii;
        } else {
            out[o] = (float)orr;
        }
    }
}

extern "C" void kernel_launch(void* const* d_in, const int* in_sizes, int n_in,
                              void* d_out, int out_size, void* d_ws, size_t ws_size,
                              hipStream_t stream)
{
    // inputs: x, Wq, Wk, Wv, Er — only x, Wk, Wv needed
    const float* x  = (const float*)d_in[0];
    const float* Wk = (const float*)d_in[2];
    const float* Wv = (const float*)d_in[3];
    float* out = (float*)d_out;

    char* ws = (char*)d_ws;
    float*  K    = (float*)(ws);                           // 2 MB
    float*  V    = (float*)(ws + (size_t)2097152);         // 2 MB
    float2* Gk   = (float2*)(ws + (size_t)4194304);        // 4 MB
    float*  part = (float*)(ws + (size_t)8388608);         // 2 KB (512 floats)
    const int out_cplx = (out_size >= 2 * 2 * 8 * 512 * 64) ? 1 : 0;

    const bool ws_big = (ws_size >= (size_t)20971520);     // needs 20 MB
    float2* Gp = ws_big ? (float2*)(ws + (size_t)8390656)  // 4 MB
                        : (float2*)d_out;                  // alias-safe fallback

    if (ws_big) {
        ushort_t* xh  = (ushort_t*)(ws + (size_t)16777216);  // 1 MB each
        ushort_t* xl  = (ushort_t*)(ws + (size_t)17825792);
        ushort_t* wth = (ushort_t*)(ws + (size_t)18874368);
        ushort_t* wtl = (ushort_t*)(ws + (size_t)19922944);
        hipLaunchKernelGGL(conv_kernel, dim3(1024), dim3(256), 0, stream,
                           x, Wk, Wv, xh, xl, wth, wtl);
        hipLaunchKernelGGL(gemm_mfma_kernel, dim3(512), dim3(256), 0, stream,
                           xh, xl, wth, wtl, K, V, part);
        hipLaunchKernelGGL(stage1_kernel, dim3(512), dim3(256), 0, stream,
                           K, V, part, Gk, Gp);
        hipLaunchKernelGGL(fft_div_kernel, dim3(512), dim3(256), 0, stream,
                           Gk, Gp, out, out_cplx);
    } else {
        hipLaunchKernelGGL(gemm_kv_kernel, dim3(512), dim3(256), 0, stream,
                           x, Wk, Wv, K, V, part);
        hipLaunchKernelGGL(stage1_kernel, dim3(512), dim3(256), 0, stream,
                           K, V, part, Gk, Gp);
        hipLaunchKernelGGL(mdft_fallback_kernel, dim3(1024), dim3(256), 0, stream,
                           Gk, Gp, out, out_cplx);
    }
}